// Round 8
// baseline (1518.538 us; speedup 1.0000x reference)
//
#include <hip/hip_runtime.h>
#include <hip/hip_bf16.h>

typedef _Float16 h16;
typedef _Float16 f16x8 __attribute__((ext_vector_type(8)));
typedef float f32x4 __attribute__((ext_vector_type(4)));

constexpr int T = 8192, H = 1024, F = 2816, E = 8;
constexpr int NENT = T * 2;
constexpr int SLACK = 128;
constexpr int BM = 256, BK = 64;
constexpr int MT256 = T / BM;       // 32
constexpr int NT1b = F / 128;       // 22
constexpr int NT2b = H / 256;       // 4
constexpr int NKH = H / BK;         // 16 (even)
constexpr int NKF = F / BK;         // 44 (even)

#define GLD16(gptr, lptr)                                                        \
  __builtin_amdgcn_global_load_lds(                                              \
      (const __attribute__((address_space(1))) unsigned int*)(gptr),             \
      (__attribute__((address_space(3))) unsigned int*)(lptr), 16, 0, 0)

#define ASM_VMCNT(n) asm volatile("s_waitcnt vmcnt(" #n ")" ::: "memory")
#define ASM_LGKM0    asm volatile("s_waitcnt lgkmcnt(0)" ::: "memory")
#define SBAR()       __builtin_amdgcn_s_barrier()
#define SCHEDB()     __builtin_amdgcn_sched_barrier(0)

// Per-half LDS tile: logical rows x 32 h16 packed as phys [rows/2][64 h16],
// XOR-swizzled 16B slots. Conflict-free with 16x16 frag reads (R2-R6).
__device__ __forceinline__ int lds_off(int row, int s) {
  int r2 = row >> 1;
  int p = (((row & 1) << 2) | s) ^ (r2 & 7);
  return r2 * 128 + p * 16;
}
__device__ __forceinline__ void inv_rowcol(int c, int i, int& row, int& col) {
  int r2 = c * 8 + (i >> 3);
  int slot8 = (i & 7) ^ (r2 & 7);
  row = r2 * 2 + (slot8 >> 2);
  col = (slot8 & 3) * 8;
}
__device__ __forceinline__ f16x8 cvt8(float4 a, float4 b) {
  return f16x8{(h16)a.x, (h16)a.y, (h16)a.z, (h16)a.w,
               (h16)b.x, (h16)b.y, (h16)b.z, (h16)b.w};
}

// ---------------- routing ----------------
__global__ void k_routing(const float* __restrict__ logits,
                          int* __restrict__ top_i, float* __restrict__ top_w,
                          int* __restrict__ counts) {
  int t = blockIdx.x * blockDim.x + threadIdx.x;
  if (t >= T) return;
  float l[E];
#pragma unroll
  for (int j = 0; j < E; ++j) l[j] = logits[t * E + j];
  int i1 = 0; float v1 = l[0];
#pragma unroll
  for (int j = 1; j < E; ++j) if (l[j] > v1) { v1 = l[j]; i1 = j; }
  int i2 = -1; float v2 = -3.4e38f;
#pragma unroll
  for (int j = 0; j < E; ++j) if (j != i1 && l[j] > v2) { v2 = l[j]; i2 = j; }
  float e2 = __expf(v2 - v1);
  float inv = 1.0f / (1.0f + e2);
  top_i[2 * t] = i1; top_i[2 * t + 1] = i2;
  top_w[2 * t] = inv; top_w[2 * t + 1] = e2 * inv;
  atomicAdd(&counts[i1], 1);
  atomicAdd(&counts[i2], 1);
}

__global__ void k_init_counts(int* counts) {
  if (threadIdx.x < E) counts[threadIdx.x] = 0;
}

__global__ void k_prefix(const int* __restrict__ counts, int* __restrict__ offs,
                         int* __restrict__ fill) {
  if (threadIdx.x == 0) {
    int s = 0;
    for (int e = 0; e < E; ++e) { offs[e] = s; s += counts[e]; fill[e] = 0; }
  }
}

__global__ void k_scatter(const int* __restrict__ top_i, const float* __restrict__ top_w,
                          const int* __restrict__ offs, int* __restrict__ fill,
                          int* __restrict__ etok, float* __restrict__ ew,
                          int* __restrict__ tok2ent) {
  int t = blockIdx.x * blockDim.x + threadIdx.x;
  if (t >= T) return;
#pragma unroll
  for (int k = 0; k < 2; ++k) {
    int e = top_i[2 * t + k];
    int pos = atomicAdd(&fill[e], 1);
    int idx = offs[e] + pos;
    etok[idx] = t;
    ew[idx] = top_w[2 * t + k];
    tok2ent[2 * t + k] = idx;
  }
}

// ---------------- fp32 -> fp16 (x only now) ----------------
__global__ void k_cvt(const float* __restrict__ s, h16* __restrict__ d) {
  size_t i = (size_t)(blockIdx.x * blockDim.x + threadIdx.x) * 8;
  float4 a = *(const float4*)(s + i);
  float4 b = *(const float4*)(s + i + 4);
  *(f16x8*)(d + i) = cvt8(a, b);
}

// ---------------- combine: out[t] = w0*y[p0] + w1*y[p1] ----------------
__global__ void k_combine(const h16* __restrict__ y, const int* __restrict__ tok2ent,
                          const float* __restrict__ topw, float* __restrict__ out) {
  int i = blockIdx.x * blockDim.x + threadIdx.x;
  int t = i >> 7;
  int h0 = (i & 127) << 3;
  int p0 = tok2ent[2 * t], p1 = tok2ent[2 * t + 1];
  float w0 = topw[2 * t], w1 = topw[2 * t + 1];
  f16x8 y0 = *(const f16x8*)(y + (size_t)p0 * H + h0);
  f16x8 y1 = *(const f16x8*)(y + (size_t)p1 * H + h0);
  float4 o0, o1;
  o0.x = w0 * (float)y0[0] + w1 * (float)y1[0];
  o0.y = w0 * (float)y0[1] + w1 * (float)y1[1];
  o0.z = w0 * (float)y0[2] + w1 * (float)y1[2];
  o0.w = w0 * (float)y0[3] + w1 * (float)y1[3];
  o1.x = w0 * (float)y0[4] + w1 * (float)y1[4];
  o1.y = w0 * (float)y0[5] + w1 * (float)y1[5];
  o1.z = w0 * (float)y0[6] + w1 * (float)y1[6];
  o1.w = w0 * (float)y0[7] + w1 * (float)y1[7];
  *(float4*)(out + (size_t)t * H + h0) = o0;
  *(float4*)(out + (size_t)t * H + h0 + 4) = o1;
}

// ---------------- GEMM1: 256x(128x2), 4-phase, fused fp32->fp16 B staging ----------------
// LDS/dbuf (64KB): A-kh0 16K | A-kh1 16K | B1-kh0 8K | B1-kh1 8K | B3-kh0 8K | B3-kh1 8K
__launch_bounds__(512, 2)
__global__ void k_gemm1(const h16* __restrict__ x16,
                        const float* __restrict__ w1f, const float* __restrict__ w3f,
                        const int* __restrict__ counts, const int* __restrict__ offs,
                        const int* __restrict__ etok, h16* __restrict__ act) {
  constexpr int NWG = E * MT256 * NT1b;              // 5632, %8==0
  int orig = blockIdx.x;
  int bid = (orig & 7) * (NWG / 8) + (orig >> 3);
  int e  = bid / (MT256 * NT1b);
  int r  = bid % (MT256 * NT1b);
  int nt = r / MT256;
  int mt = r % MT256;
  int n_e = counts[e];
  if (mt * BM >= n_e) return;
  int base = offs[e];

  __shared__ char lds[131072];

  int tid = threadIdx.x;
  int lane = tid & 63, wid = tid >> 6;
  int wm = (wid >> 2) * 128;
  int wn = (wid & 3) * 32;
  int lr = lane & 15, ls = lane >> 4;

  auto Ab  = [&](int d, int h) -> char* { return lds + d * 65536 + h * 16384; };
  auto B1b = [&](int d, int h) -> char* { return lds + d * 65536 + 32768 + h * 8192; };
  auto B3b = [&](int d, int h) -> char* { return lds + d * 65536 + 49152 + h * 8192; };

  const h16* gA[2];
#pragma unroll
  for (int j = 0; j < 2; ++j) {
    int row, col;
    inv_rowcol(2 * wid + j, lane, row, col);
    int gr = mt * BM + row; if (gr >= n_e) gr = n_e - 1;
    gA[j] = x16 + (size_t)etok[base + gr] * H + col;
  }
  const float *fB1, *fB3;
  {
    int row, col;
    inv_rowcol(wid, lane, row, col);
    size_t w = ((size_t)e * F + (size_t)nt * 128 + row) * H + col;
    fB1 = w1f + w;
    fB3 = w3f + w;
  }

  auto stA = [&](int d, int h, int kt) {
#pragma unroll
    for (int j = 0; j < 2; ++j)
      GLD16(gA[j] + kt * 64 + h * 32, Ab(d, h) + (2 * wid + j) * 1024);
  };

  int aoff[8], boff[2];
#pragma unroll
  for (int mi = 0; mi < 8; ++mi) aoff[mi] = lds_off(wm + mi * 16 + lr, ls);
#pragma unroll
  for (int nj = 0; nj < 2; ++nj) boff[nj] = lds_off(wn + nj * 16 + lr, ls);

  f32x4 ag[8][2] = {{{0.f,0.f,0.f,0.f}}};
  f32x4 au[8][2] = {{{0.f,0.f,0.f,0.f}}};

  // B reg sets: [0,1]=B1 kh0, [2,3]=B1 kh1, [4,5]=B3 kh0, [6,7]=B3 kh1
  float4 bsetA[8], bsetB[8];

#define G1_ISSUE(S, KT)                                                          \
  _Pragma("unroll") for (int q = 0; q < 2; ++q) {                                \
    S[q]     = *(const float4*)(fB1 + (KT) * 64 + q * 4);                        \
    S[2 + q] = *(const float4*)(fB1 + (KT) * 64 + 32 + q * 4);                   \
    S[4 + q] = *(const float4*)(fB3 + (KT) * 64 + q * 4);                        \
    S[6 + q] = *(const float4*)(fB3 + (KT) * 64 + 32 + q * 4);                   \
  }
#define G1_WRITE0(S, D)                                                          \
  *(f16x8*)(B1b(D, 0) + wid * 1024 + lane * 16) = cvt8(S[0], S[1]);              \
  *(f16x8*)(B3b(D, 0) + wid * 1024 + lane * 16) = cvt8(S[4], S[5]);
#define G1_WRITE1(S, D)                                                          \
  *(f16x8*)(B1b(D, 1) + wid * 1024 + lane * 16) = cvt8(S[2], S[3]);              \
  *(f16x8*)(B3b(D, 1) + wid * 1024 + lane * 16) = cvt8(S[6], S[7]);

#define G1_MFMA(MI0, AF, B1F, B3F)                                               \
  __builtin_amdgcn_s_setprio(1);                                                 \
  _Pragma("unroll") for (int m = 0; m < 4; ++m)                                  \
  _Pragma("unroll") for (int nj = 0; nj < 2; ++nj) {                             \
    ag[MI0 + m][nj] = __builtin_amdgcn_mfma_f32_16x16x32_f16(AF[m], B1F[nj], ag[MI0 + m][nj], 0, 0, 0); \
    au[MI0 + m][nj] = __builtin_amdgcn_mfma_f32_16x16x32_f16(AF[m], B3F[nj], au[MI0 + m][nj], 0, 0, 0); \
  }                                                                              \
  __builtin_amdgcn_s_setprio(0);

#define G1_TILE(TT, SCUR, SNEXT)                                                 \
  {                                                                              \
    const int t_ = (TT);                                                         \
    const int cur_ = t_ & 1;                                                     \
    /* ph0: read A mi0-3 kh0 + B kh0; GLD16 A-kh1(t+1); issue B fp32 (t+2) */    \
    f16x8 aL0[4], b1k0[2], b3k0[2];                                              \
    _Pragma("unroll") for (int m = 0; m < 4; ++m)                                \
      aL0[m] = *(const f16x8*)(Ab(cur_, 0) + aoff[m]);                           \
    _Pragma("unroll") for (int nj = 0; nj < 2; ++nj) {                           \
      b1k0[nj] = *(const f16x8*)(B1b(cur_, 0) + boff[nj]);                       \
      b3k0[nj] = *(const f16x8*)(B3b(cur_, 0) + boff[nj]);                       \
    }                                                                            \
    if (t_ + 1 < NKH) stA(cur_ ^ 1, 1, t_ + 1);                                  \
    SCHEDB();                                                                    \
    if (t_ + 2 < NKH) { G1_ISSUE(SNEXT, t_ + 2) }                                \
    SBAR();                                                                      \
    G1_MFMA(0, aL0, b1k0, b3k0)                                                  \
    SBAR();                                                                      \
    /* ph1: read A mi0-3 kh1 + B kh1; cvt+write B(t+1) kh0 */                    \
    f16x8 aL1[4], b1k1[2], b3k1[2];                                              \
    _Pragma("unroll") for (int m = 0; m < 4; ++m)                                \
      aL1[m] = *(const f16x8*)(Ab(cur_, 1) + aoff[m]);                           \
    _Pragma("unroll") for (int nj = 0; nj < 2; ++nj) {                           \
      b1k1[nj] = *(const f16x8*)(B1b(cur_, 1) + boff[nj]);                       \
      b3k1[nj] = *(const f16x8*)(B3b(cur_, 1) + boff[nj]);                       \
    }                                                                            \
    if (t_ + 1 < NKH) { G1_WRITE0(SCUR, cur_ ^ 1) }                              \
    SBAR();                                                                      \
    G1_MFMA(0, aL1, b1k1, b3k1)                                                  \
    SBAR();                                                                      \
    /* ph2: read A mi4-7 kh0; cvt+write B(t+1) kh1 */                            \
    f16x8 aH0[4];                                                                \
    _Pragma("unroll") for (int m = 0; m < 4; ++m)                                \
      aH0[m] = *(const f16x8*)(Ab(cur_, 0) + aoff[4 + m]);                       \
    if (t_ + 1 < NKH) { G1_WRITE1(SCUR, cur_ ^ 1) }                              \
    SBAR();                                                                      \
    G1_MFMA(4, aH0, b1k0, b3k0)                                                  \
    SBAR();                                                                      \
    /* ph3: read A mi4-7 kh1; GLD16 A-kh0(t+2); counted vmcnt + lgkm fence */    \
    f16x8 aH1[4];                                                                \
    _Pragma("unroll") for (int m = 0; m < 4; ++m)                                \
      aH1[m] = *(const f16x8*)(Ab(cur_, 1) + aoff[4 + m]);                       \
    if (t_ + 2 < NKH) stA(cur_, 0, t_ + 2);                                      \
    SBAR();                                                                      \
    G1_MFMA(4, aH1, b1k1, b3k1)                                                  \
    if (t_ + 2 < NKH) { ASM_VMCNT(10); } else { ASM_VMCNT(0); }                  \
    ASM_LGKM0;                                                                   \
    SBAR();                                                                      \
  }

  // prologue: A GLD16s first (FIFO-oldest), then B(0) sync, then B(1) issue
  stA(0, 0, 0); stA(0, 1, 0); stA(1, 0, 1);
  SCHEDB();
  G1_ISSUE(bsetB, 0)
  G1_WRITE0(bsetB, 0)
  G1_WRITE1(bsetB, 0)
  SCHEDB();
  G1_ISSUE(bsetA, 1)
  ASM_VMCNT(8);
  ASM_LGKM0;
  SBAR();

  for (int t2 = 0; t2 < NKH; t2 += 2) {
    G1_TILE(t2,     bsetA, bsetB)
    G1_TILE(t2 + 1, bsetB, bsetA)
  }
#undef G1_TILE
#undef G1_MFMA
#undef G1_ISSUE
#undef G1_WRITE0
#undef G1_WRITE1

  // epilogue: silu(g)*u -> act fp16
#pragma unroll
  for (int mi = 0; mi < 8; ++mi) {
#pragma unroll
    for (int rr = 0; rr < 4; ++rr) {
      int grow = mt * BM + wm + mi * 16 + ls * 4 + rr;
      if (grow < n_e) {
        size_t rowb = (size_t)(base + grow) * F + (size_t)nt * 128 + wn;
#pragma unroll
        for (int nj = 0; nj < 2; ++nj) {
          float g = ag[mi][nj][rr];
          float u = au[mi][nj][rr];
          float s = g / (1.0f + __expf(-g)) * u;
          act[rowb + nj * 16 + lr] = (h16)s;
        }
      }
    }
  }
}

// ---------------- GEMM2: 256x256, 4-phase, fused fp32->fp16 B staging ----------------
// LDS/dbuf (64KB): A-kh0 16K | A-kh1 16K | B-kh0 16K | B-kh1 16K
__launch_bounds__(512, 2)
__global__ void k_gemm2(const h16* __restrict__ act, const float* __restrict__ w2f,
                        const int* __restrict__ counts, const int* __restrict__ offs,
                        h16* __restrict__ y16) {
  constexpr int NWG = E * MT256 * NT2b;              // 1024, %8==0
  int orig = blockIdx.x;
  int bid = (orig & 7) * (NWG / 8) + (orig >> 3);
  int e  = bid / (MT256 * NT2b);
  int r  = bid % (MT256 * NT2b);
  int nt = r / MT256;
  int mt = r % MT256;
  int n_e = counts[e];
  if (mt * BM >= n_e) return;
  int base = offs[e];

  __shared__ char lds[131072];

  int tid = threadIdx.x;
  int lane = tid & 63, wid = tid >> 6;
  int wm = (wid >> 2) * 128;
  int wn = (wid & 3) * 64;
  int lr = lane & 15, ls = lane >> 4;

  auto Ab = [&](int d, int h) -> char* { return lds + d * 65536 + h * 16384; };
  auto Bb = [&](int d, int h) -> char* { return lds + d * 65536 + 32768 + h * 16384; };

  const h16* gA[2];
  const float* fB[2];
#pragma unroll
  for (int j = 0; j < 2; ++j) {
    int row, col;
    inv_rowcol(2 * wid + j, lane, row, col);
    int gr = mt * BM + row; if (gr >= n_e) gr = n_e - 1;
    gA[j] = act + (size_t)(base + gr) * F + col;
    fB[j] = w2f + ((size_t)e * H + (size_t)nt * 256 + row) * F + col;
  }

  auto stA = [&](int d, int h, int kt) {
#pragma unroll
    for (int j = 0; j < 2; ++j)
      GLD16(gA[j] + kt * 64 + h * 32, Ab(d, h) + (2 * wid + j) * 1024);
  };

  int aoff[8], boff[4];
#pragma unroll
  for (int mi = 0; mi < 8; ++mi) aoff[mi] = lds_off(wm + mi * 16 + lr, ls);
#pragma unroll
  for (int nj = 0; nj < 4; ++nj) boff[nj] = lds_off(wn + nj * 16 + lr, ls);

  f32x4 acc[8][4] = {{{0.f,0.f,0.f,0.f}}};

  // B reg sets: [j*4 + 0,1] = chunk j kh0, [j*4 + 2,3] = chunk j kh1
  float4 bsetA[8], bsetB[8];

#define G2_ISSUE(S, KT)                                                          \
  _Pragma("unroll") for (int j = 0; j < 2; ++j) {                                \
    S[j * 4 + 0] = *(const float4*)(fB[j] + (KT) * 64);                          \
    S[j * 4 + 1] = *(const float4*)(fB[j] + (KT) * 64 + 4);                      \
    S[j * 4 + 2] = *(const float4*)(fB[j] + (KT) * 64 + 32);                     \
    S[j * 4 + 3] = *(const float4*)(fB[j] + (KT) * 64 + 36);                     \
  }
#define G2_WRITE0(S, D)                                                          \
  _Pragma("unroll") for (int j = 0; j < 2; ++j)                                  \
    *(f16x8*)(Bb(D, 0) + (2 * wid + j) * 1024 + lane * 16) =                     \
        cvt8(S[j * 4 + 0], S[j * 4 + 1]);
#define G2_WRITE1(S, D)                                                          \
  _Pragma("unroll") for (int j = 0; j < 2; ++j)                                  \
    *(f16x8*)(Bb(D, 1) + (2 * wid + j) * 1024 + lane * 16) =                     \
        cvt8(S[j * 4 + 2], S[j * 4 + 3]);

#define G2_MFMA(MI0, AF, BF)                                                     \
  __builtin_amdgcn_s_setprio(1);                                                 \
  _Pragma("unroll") for (int m = 0; m < 4; ++m)                                  \
  _Pragma("unroll") for (int nj = 0; nj < 4; ++nj) {                             \
    acc[MI0 + m][nj] = __builtin_amdgcn_mfma_f32_16x16x32_f16(AF[m], BF[nj], acc[MI0 + m][nj], 0, 0, 0); \
  }                                                                              \
  __builtin_amdgcn_s_setprio(0);

#define G2_TILE(TT, SCUR, SNEXT)                                                 \
  {                                                                              \
    const int t_ = (TT);                                                         \
    const int cur_ = t_ & 1;                                                     \
    f16x8 aL0[4], bk0[4];                                                        \
    _Pragma("unroll") for (int m = 0; m < 4; ++m)                                \
      aL0[m] = *(const f16x8*)(Ab(cur_, 0) + aoff[m]);                           \
    _Pragma("unroll") for (int nj = 0; nj < 4; ++nj)                             \
      bk0[nj] = *(const f16x8*)(Bb(cur_, 0) + boff[nj]);                         \
    if (t_ + 1 < NKF) stA(cur_ ^ 1, 1, t_ + 1);                                  \
    SCHEDB();                                                                    \
    if (t_ + 2 < NKF) { G2_ISSUE(SNEXT, t_ + 2) }                                \
    SBAR();                                                                      \
    G2_MFMA(0, aL0, bk0)                                                         \
    SBAR();                                                                      \
    f16x8 aL1[4], bk1[4];                                                        \
    _Pragma("unroll") for (int m = 0; m < 4; ++m)                                \
      aL1[m] = *(const f16x8*)(Ab(cur_, 1) + aoff[m]);                           \
    _Pragma("unroll") for (int nj = 0; nj < 4; ++nj)                             \
      bk1[nj] = *(const f16x8*)(Bb(cur_, 1) + boff[nj]);                         \
    if (t_ + 1 < NKF) { G2_WRITE0(SCUR, cur_ ^ 1) }                              \
    SBAR();                                                                      \
    G2_MFMA(0, aL1, bk1)                                                         \
    SBAR();                                                                      \
    f16x8 aH0[4];                                                                \
    _Pragma("unroll") for (int m = 0; m < 4; ++m)                                \
      aH0[m] = *(const f16x8*)(Ab(cur_, 0) + aoff[4 + m]);                       \
    if (t_ + 1 < NKF) { G2_WRITE1(SCUR, cur_ ^ 1) }                              \
    SBAR();                                                                      \
    G2_MFMA(4, aH0, bk0)                                                         \
    SBAR();                                                                      \
    f16x8 aH1[4];                                                                \
    _Pragma("unroll") for (int m = 0; m < 4; ++m)                                \
      aH1[m] = *(const f16x8*)(Ab(cur_, 1) + aoff[4 + m]);                       \
    if (t_ + 2 < NKF) stA(cur_, 0, t_ + 2);                                      \
    SBAR();                                                                      \
    G2_MFMA(4, aH1, bk1)                                                         \
    if (t_ + 2 < NKF) { ASM_VMCNT(10); } else { ASM_VMCNT(0); }                  \
    ASM_LGKM0;                                                                   \
    SBAR();                                                                      \
  }

  stA(0, 0, 0); stA(0, 1, 0); stA(1, 0, 1);
  SCHEDB();
  G2_ISSUE(bsetB, 0)
  G2_WRITE0(bsetB, 0)
  G2_WRITE1(bsetB, 0)
  SCHEDB();
  G2_ISSUE(bsetA, 1)
  ASM_VMCNT(8);
  ASM_LGKM0;
  SBAR();

  for (int t2 = 0; t2 < NKF; t2 += 2) {
    G2_TILE(t2,     bsetA, bsetB)
    G2_TILE(t2 + 1, bsetB, bsetA)
  }
#undef G2_TILE
#undef G2_MFMA
#undef G2_ISSUE
#undef G2_WRITE0
#undef G2_WRITE1

#pragma unroll
  for (int mi = 0; mi < 8; ++mi) {
#pragma unroll
    for (int rr = 0; rr < 4; ++rr) {
      int grow = mt * BM + wm + mi * 16 + ls * 4 + rr;
      if (grow < n_e) {
        h16* yrow = y16 + (size_t)(base + grow) * H + (size_t)nt * 256 + wn;
#pragma unroll
        for (int nj = 0; nj < 4; ++nj)
          yrow[nj * 16 + lr] = (h16)acc[mi][nj][rr];
      }
    }
  }
}

extern "C" void kernel_launch(void* const* d_in, const int* in_sizes, int n_in,
                              void* d_out, int out_size, void* d_ws, size_t ws_size,
                              hipStream_t stream) {
  const float* x  = (const float*)d_in[0];
  const float* rl = (const float*)d_in[1];
  const float* w1 = (const float*)d_in[2];
  const float* w3 = (const float*)d_in[3];
  const float* w2 = (const float*)d_in[4];
  float* out = (float*)d_out;

  char* ws = (char*)d_ws;
  size_t off = 0;
  auto alloc = [&](size_t bytes) -> void* {
    void* p = ws + off;
    off = (off + bytes + 255) & ~(size_t)255;
    return p;
  };
  h16*   x16  = (h16*)  alloc((size_t)T * H * sizeof(h16));
  h16*   act  = (h16*)  alloc((size_t)(NENT + SLACK) * F * sizeof(h16));
  int*   etok = (int*)  alloc((size_t)(NENT + SLACK) * sizeof(int));
  float* ew   = (float*)alloc((size_t)(NENT + SLACK) * sizeof(float));
  int*   topi = (int*)  alloc((size_t)NENT * sizeof(int));
  float* topw = (float*)alloc((size_t)NENT * sizeof(float));
  int* tok2ent = (int*) alloc((size_t)NENT * sizeof(int));
  int* counts = (int*)  alloc(64);
  int* offs   = (int*)  alloc(64);
  int* fill   = (int*)  alloc(64);
  h16* y16 = (h16*)alloc((size_t)(NENT + SLACK) * H * sizeof(h16));
  (void)in_sizes; (void)n_in; (void)ws_size;

  k_init_counts<<<1, 64, 0, stream>>>(counts);
  k_routing<<<(T + 255) / 256, 256, 0, stream>>>(rl, topi, topw, counts);
  k_prefix<<<1, 64, 0, stream>>>(counts, offs, fill);
  k_scatter<<<(T + 255) / 256, 256, 0, stream>>>(topi, topw, offs, fill, etok, ew, tok2ent);
  k_cvt<<<(T * H / 8) / 256, 256, 0, stream>>>(x, x16);
  k_gemm1<<<E * MT256 * NT1b, 512, 0, stream>>>(x16, w1, w3, counts, offs, etok, act);
  k_gemm2<<<E * MT256 * NT2b, 512, 0, stream>>>(act, w2, counts, offs, y16);
  k_combine<<<(T * H / 8) / 256, 256, 0, stream>>>(y16, tok2ent, topw, out);
}

// Round 9
// 607.758 us; speedup vs baseline: 2.4986x; 2.4986x over previous
//
#include <hip/hip_runtime.h>
#include <hip/hip_bf16.h>

typedef _Float16 h16;
typedef _Float16 f16x8 __attribute__((ext_vector_type(8)));
typedef float f32x4 __attribute__((ext_vector_type(4)));

constexpr int T = 8192, H = 1024, F = 2816, E = 8;
constexpr int NENT = T * 2;
constexpr int SLACK = 128;
constexpr int BM = 256, BK = 64;
constexpr int MT256 = T / BM;       // 32
constexpr int NT1b = F / 128;       // 22
constexpr int NT2b = H / 256;       // 4
constexpr int NKH = H / BK;         // 16
constexpr int NKF = F / BK;         // 44
constexpr int NWG1 = E * MT256 * NT1b;   // 5632 gemm1 blocks
constexpr int CVT2_BLKS = 704;           // w2 cvt blocks: 704*512*64 = E*H*F
constexpr int NX = T * H;                // 8388608
constexpr int NW = E * F * H;            // 23068672
constexpr int RT_BLKS = 32;              // routing blocks (32*256 = T)
constexpr int CVT1_BLKS = 2048;          // (NX + 2*NW) / 26624 = 2048 exactly
constexpr int CVT1_PER = 26624;          // elems per cvt block (256*8*13)

#define GLD16(gptr, lptr)                                                        \
  __builtin_amdgcn_global_load_lds(                                              \
      (const __attribute__((address_space(1))) unsigned int*)(gptr),             \
      (__attribute__((address_space(3))) unsigned int*)(lptr), 16, 0, 0)

#define ASM_VMCNT(n) asm volatile("s_waitcnt vmcnt(" #n ")" ::: "memory")
#define SBAR()       __builtin_amdgcn_s_barrier()

// Per-half LDS tile: logical rows x 32 h16 packed as phys [rows/2][64 h16],
// XOR-swizzled 16B slots. Conflict-free with 16x16 frag reads (R2-R6).
__device__ __forceinline__ int lds_off(int row, int s) {
  int r2 = row >> 1;
  int p = (((row & 1) << 2) | s) ^ (r2 & 7);
  return r2 * 128 + p * 16;
}
__device__ __forceinline__ void inv_rowcol(int c, int i, int& row, int& col) {
  int r2 = c * 8 + (i >> 3);
  int slot8 = (i & 7) ^ (r2 & 7);
  row = r2 * 2 + (slot8 >> 2);
  col = (slot8 & 3) * 8;
}
__device__ __forceinline__ f16x8 cvt8(float4 a, float4 b) {
  return f16x8{(h16)a.x, (h16)a.y, (h16)a.z, (h16)a.w,
               (h16)b.x, (h16)b.y, (h16)b.z, (h16)b.w};
}

__global__ void k_init_counts(int* counts) {
  if (threadIdx.x < E) counts[threadIdx.x] = 0;
}

// ---------------- fused routing + x/w1/w3 fp32->fp16 conversion ----------------
__global__ void k_route_cvt(const float* __restrict__ logits,
                            int* __restrict__ top_i, float* __restrict__ top_w,
                            int* __restrict__ counts,
                            const float* __restrict__ x, h16* __restrict__ x16,
                            const float* __restrict__ w1, h16* __restrict__ w1h,
                            const float* __restrict__ w3, h16* __restrict__ w3h) {
  int blk = blockIdx.x;
  if (blk < RT_BLKS) {
    int t = blk * blockDim.x + threadIdx.x;
    if (t >= T) return;
    float l[E];
#pragma unroll
    for (int j = 0; j < E; ++j) l[j] = logits[t * E + j];
    int i1 = 0; float v1 = l[0];
#pragma unroll
    for (int j = 1; j < E; ++j) if (l[j] > v1) { v1 = l[j]; i1 = j; }
    int i2 = -1; float v2 = -3.4e38f;
#pragma unroll
    for (int j = 0; j < E; ++j) if (j != i1 && l[j] > v2) { v2 = l[j]; i2 = j; }
    float e2 = __expf(v2 - v1);
    float inv = 1.0f / (1.0f + e2);
    top_i[2 * t] = i1; top_i[2 * t + 1] = i2;
    top_w[2 * t] = inv; top_w[2 * t + 1] = e2 * inv;
    atomicAdd(&counts[i1], 1);
    atomicAdd(&counts[i2], 1);
    return;
  }
  // conversion blocks: flat range [0, NX + 2*NW), 8 elems/thread, 13 iters
  size_t base = (size_t)(blk - RT_BLKS) * CVT1_PER + threadIdx.x * 8;
#pragma unroll
  for (int it = 0; it < 13; ++it) {
    size_t idx = base + (size_t)it * 2048;
    const float* s; h16* d; size_t o;
    if (idx < (size_t)NX)            { s = x;  d = x16; o = idx; }
    else if (idx < (size_t)NX + NW)  { s = w1; d = w1h; o = idx - NX; }
    else                             { s = w3; d = w3h; o = idx - NX - NW; }
    float4 a = *(const float4*)(s + o);
    float4 b = *(const float4*)(s + o + 4);
    *(f16x8*)(d + o) = cvt8(a, b);
  }
}

__global__ void k_prefix(const int* __restrict__ counts, int* __restrict__ offs,
                         int* __restrict__ fill) {
  if (threadIdx.x == 0) {
    int s = 0;
    for (int e = 0; e < E; ++e) { offs[e] = s; s += counts[e]; fill[e] = 0; }
  }
}

__global__ void k_scatter(const int* __restrict__ top_i, const float* __restrict__ top_w,
                          const int* __restrict__ offs, int* __restrict__ fill,
                          int* __restrict__ etok, float* __restrict__ ew,
                          int* __restrict__ tok2ent) {
  int t = blockIdx.x * blockDim.x + threadIdx.x;
  if (t >= T) return;
#pragma unroll
  for (int k = 0; k < 2; ++k) {
    int e = top_i[2 * t + k];
    int pos = atomicAdd(&fill[e], 1);
    int idx = offs[e] + pos;
    etok[idx] = t;
    ew[idx] = top_w[2 * t + k];
    tok2ent[2 * t + k] = idx;
  }
}

// ---------------- combine: out[t] = w0*y[p0] + w1*y[p1] ----------------
__global__ void k_combine(const h16* __restrict__ y, const int* __restrict__ tok2ent,
                          const float* __restrict__ topw, float* __restrict__ out) {
  int i = blockIdx.x * blockDim.x + threadIdx.x;
  int t = i >> 7;
  int h0 = (i & 127) << 3;
  int p0 = tok2ent[2 * t], p1 = tok2ent[2 * t + 1];
  float w0 = topw[2 * t], w1 = topw[2 * t + 1];
  f16x8 y0 = *(const f16x8*)(y + (size_t)p0 * H + h0);
  f16x8 y1 = *(const f16x8*)(y + (size_t)p1 * H + h0);
  float4 o0, o1;
  o0.x = w0 * (float)y0[0] + w1 * (float)y1[0];
  o0.y = w0 * (float)y0[1] + w1 * (float)y1[1];
  o0.z = w0 * (float)y0[2] + w1 * (float)y1[2];
  o0.w = w0 * (float)y0[3] + w1 * (float)y1[3];
  o1.x = w0 * (float)y0[4] + w1 * (float)y1[4];
  o1.y = w0 * (float)y0[5] + w1 * (float)y1[5];
  o1.z = w0 * (float)y0[6] + w1 * (float)y1[6];
  o1.w = w0 * (float)y0[7] + w1 * (float)y1[7];
  *(float4*)(out + (size_t)t * H + h0) = o0;
  *(float4*)(out + (size_t)t * H + h0 + 4) = o1;
}

// ---------------- GEMM1: 256x(128x2), 4-phase/K-tile (R6) + w2-cvt tail blocks ----------------
// LDS per dbuf (64KB): A-kh0 16K | A-kh1 16K | B1-kh0 8K | B1-kh1 8K | B3-kh0 8K | B3-kh1 8K
__launch_bounds__(512, 2)
__global__ void k_gemm1(const h16* __restrict__ x16,
                        const h16* __restrict__ w1h, const h16* __restrict__ w3h,
                        const int* __restrict__ counts, const int* __restrict__ offs,
                        const int* __restrict__ etok, h16* __restrict__ act,
                        const float* __restrict__ w2f, h16* __restrict__ w2h) {
  int orig = blockIdx.x;
  if (orig >= NWG1) {
    // w2 fp32->fp16 conversion: 704 blocks x 512 thr x 8 elems x 8 iters
    size_t base = (size_t)(orig - NWG1) * (512 * 64) + threadIdx.x * 8;
#pragma unroll
    for (int it = 0; it < 8; ++it) {
      size_t o = base + (size_t)it * (512 * 8);
      float4 a = *(const float4*)(w2f + o);
      float4 b = *(const float4*)(w2f + o + 4);
      *(f16x8*)(w2h + o) = cvt8(a, b);
    }
    return;
  }
  int bid = (orig & 7) * (NWG1 / 8) + (orig >> 3);   // XCD-chunked swizzle
  int e  = bid / (MT256 * NT1b);
  int r  = bid % (MT256 * NT1b);
  int nt = r / MT256;
  int mt = r % MT256;
  int n_e = counts[e];
  if (mt * BM >= n_e) return;
  int base = offs[e];

  __shared__ char lds[131072];

  int tid = threadIdx.x;
  int lane = tid & 63, wid = tid >> 6;
  int wm = (wid >> 2) * 128;
  int wn = (wid & 3) * 32;
  int lr = lane & 15, ls = lane >> 4;

  auto Ab  = [&](int d, int h) -> char* { return lds + d * 65536 + h * 16384; };
  auto B1b = [&](int d, int h) -> char* { return lds + d * 65536 + 32768 + h * 8192; };
  auto B3b = [&](int d, int h) -> char* { return lds + d * 65536 + 49152 + h * 8192; };

  const h16* gA[2];
#pragma unroll
  for (int j = 0; j < 2; ++j) {
    int row, col;
    inv_rowcol(2 * wid + j, lane, row, col);
    int gr = mt * BM + row; if (gr >= n_e) gr = n_e - 1;
    gA[j] = x16 + (size_t)etok[base + gr] * H + col;
  }
  const h16 *gB1, *gB3;
  {
    int row, col;
    inv_rowcol(wid, lane, row, col);
    size_t w = ((size_t)e * F + (size_t)nt * 128 + row) * H + col;
    gB1 = w1h + w;
    gB3 = w3h + w;
  }

  auto stA = [&](int d, int h, int kt) {
#pragma unroll
    for (int j = 0; j < 2; ++j)
      GLD16(gA[j] + kt * 64 + h * 32, Ab(d, h) + (2 * wid + j) * 1024);
  };
  auto stB = [&](int d, int h, int kt) {
    GLD16(gB1 + kt * 64 + h * 32, B1b(d, h) + wid * 1024);
    GLD16(gB3 + kt * 64 + h * 32, B3b(d, h) + wid * 1024);
  };

  int aoff[8], boff[2];
#pragma unroll
  for (int mi = 0; mi < 8; ++mi) aoff[mi] = lds_off(wm + mi * 16 + lr, ls);
#pragma unroll
  for (int nj = 0; nj < 2; ++nj) boff[nj] = lds_off(wn + nj * 16 + lr, ls);

  f32x4 ag[8][2] = {{{0.f,0.f,0.f,0.f}}};
  f32x4 au[8][2] = {{{0.f,0.f,0.f,0.f}}};

#define G1_MFMA(MI0, AF, B1F, B3F)                                               \
  __builtin_amdgcn_s_setprio(1);                                                 \
  _Pragma("unroll") for (int m = 0; m < 4; ++m)                                  \
  _Pragma("unroll") for (int nj = 0; nj < 2; ++nj) {                             \
    ag[MI0 + m][nj] = __builtin_amdgcn_mfma_f32_16x16x32_f16(AF[m], B1F[nj], ag[MI0 + m][nj], 0, 0, 0); \
    au[MI0 + m][nj] = __builtin_amdgcn_mfma_f32_16x16x32_f16(AF[m], B3F[nj], au[MI0 + m][nj], 0, 0, 0); \
  }                                                                              \
  __builtin_amdgcn_s_setprio(0);

  // prologue: tile0 fully (8), tile1 all but A-kh1 (6)
  stA(0, 0, 0); stB(0, 0, 0); stB(0, 1, 0); stA(0, 1, 0);
  stB(1, 0, 1); stB(1, 1, 1); stA(1, 0, 1);
  ASM_VMCNT(6);
  SBAR();

  for (int t = 0; t < NKH; ++t) {
    int cur = t & 1;
    // ph0: A[0-3]kh0 + B kh0 reads; stage A-kh1(t+1) -> dbuf cur^1
    f16x8 aL0[4], b1k0[2], b3k0[2];
#pragma unroll
    for (int m = 0; m < 4; ++m) aL0[m] = *(const f16x8*)(Ab(cur, 0) + aoff[m]);
#pragma unroll
    for (int nj = 0; nj < 2; ++nj) {
      b1k0[nj] = *(const f16x8*)(B1b(cur, 0) + boff[nj]);
      b3k0[nj] = *(const f16x8*)(B3b(cur, 0) + boff[nj]);
    }
    if (t + 1 < NKH) stA(cur ^ 1, 1, t + 1);
    SBAR();
    G1_MFMA(0, aL0, b1k0, b3k0)
    SBAR();
    // ph1: A[0-3]kh1 + B kh1 reads; stage B-kh0(t+2) -> cur
    f16x8 aL1[4], b1k1[2], b3k1[2];
#pragma unroll
    for (int m = 0; m < 4; ++m) aL1[m] = *(const f16x8*)(Ab(cur, 1) + aoff[m]);
#pragma unroll
    for (int nj = 0; nj < 2; ++nj) {
      b1k1[nj] = *(const f16x8*)(B1b(cur, 1) + boff[nj]);
      b3k1[nj] = *(const f16x8*)(B3b(cur, 1) + boff[nj]);
    }
    if (t + 2 < NKH) stB(cur, 0, t + 2);
    SBAR();
    G1_MFMA(0, aL1, b1k1, b3k1)
    SBAR();
    // ph2: A[4-7]kh0 reads; stage B-kh1(t+2) -> cur
    f16x8 aH0[4];
#pragma unroll
    for (int m = 0; m < 4; ++m) aH0[m] = *(const f16x8*)(Ab(cur, 0) + aoff[4 + m]);
    if (t + 2 < NKH) stB(cur, 1, t + 2);
    SBAR();
    G1_MFMA(4, aH0, b1k0, b3k0)
    SBAR();
    // ph3: A[4-7]kh1 reads; stage A-kh0(t+2) -> cur; counted vmcnt
    f16x8 aH1[4];
#pragma unroll
    for (int m = 0; m < 4; ++m) aH1[m] = *(const f16x8*)(Ab(cur, 1) + aoff[4 + m]);
    if (t + 2 < NKH) stA(cur, 0, t + 2);
    SBAR();
    G1_MFMA(4, aH1, b1k1, b3k1)
    if (t + 2 < NKH) { ASM_VMCNT(6); } else { ASM_VMCNT(0); }
    SBAR();
  }
#undef G1_MFMA

  // epilogue: silu(g)*u -> act fp16
#pragma unroll
  for (int mi = 0; mi < 8; ++mi) {
#pragma unroll
    for (int rr = 0; rr < 4; ++rr) {
      int grow = mt * BM + wm + mi * 16 + ls * 4 + rr;
      if (grow < n_e) {
        size_t rowb = (size_t)(base + grow) * F + (size_t)nt * 128 + wn;
#pragma unroll
        for (int nj = 0; nj < 2; ++nj) {
          float g = ag[mi][nj][rr];
          float u = au[mi][nj][rr];
          float s = g / (1.0f + __expf(-g)) * u;
          act[rowb + nj * 16 + lr] = (h16)s;
        }
      }
    }
  }
}

// ---------------- GEMM2: 256x256, 4-phase/K-tile (R6) ----------------
// LDS per dbuf (64KB): A-kh0 16K | A-kh1 16K | B-kh0 16K | B-kh1 16K
__launch_bounds__(512, 2)
__global__ void k_gemm2(const h16* __restrict__ act, const h16* __restrict__ w2h,
                        const int* __restrict__ counts, const int* __restrict__ offs,
                        h16* __restrict__ y16) {
  constexpr int NWG = E * MT256 * NT2b;              // 1024, %8==0
  int orig = blockIdx.x;
  int bid = (orig & 7) * (NWG / 8) + (orig >> 3);
  int e  = bid / (MT256 * NT2b);
  int r  = bid % (MT256 * NT2b);
  int nt = r / MT256;
  int mt = r % MT256;
  int n_e = counts[e];
  if (mt * BM >= n_e) return;
  int base = offs[e];

  __shared__ char lds[131072];

  int tid = threadIdx.x;
  int lane = tid & 63, wid = tid >> 6;
  int wm = (wid >> 2) * 128;
  int wn = (wid & 3) * 64;
  int lr = lane & 15, ls = lane >> 4;

  auto Ab = [&](int d, int h) -> char* { return lds + d * 65536 + h * 16384; };
  auto Bb = [&](int d, int h) -> char* { return lds + d * 65536 + 32768 + h * 16384; };

  const h16* gA[2]; const h16* gB[2];
#pragma unroll
  for (int j = 0; j < 2; ++j) {
    int row, col;
    inv_rowcol(2 * wid + j, lane, row, col);
    int gr = mt * BM + row; if (gr >= n_e) gr = n_e - 1;
    gA[j] = act + (size_t)(base + gr) * F + col;
    gB[j] = w2h + ((size_t)e * H + (size_t)nt * 256 + row) * F + col;
  }

  auto stA = [&](int d, int h, int kt) {
#pragma unroll
    for (int j = 0; j < 2; ++j)
      GLD16(gA[j] + kt * 64 + h * 32, Ab(d, h) + (2 * wid + j) * 1024);
  };
  auto stB = [&](int d, int h, int kt) {
#pragma unroll
    for (int j = 0; j < 2; ++j)
      GLD16(gB[j] + kt * 64 + h * 32, Bb(d, h) + (2 * wid + j) * 1024);
  };

  int aoff[8], boff[4];
#pragma unroll
  for (int mi = 0; mi < 8; ++mi) aoff[mi] = lds_off(wm + mi * 16 + lr, ls);
#pragma unroll
  for (int nj = 0; nj < 4; ++nj) boff[nj] = lds_off(wn + nj * 16 + lr, ls);

  f32x4 acc[8][4] = {{{0.f,0.f,0.f,0.f}}};

#define G2_MFMA(MI0, AF, BF)                                                     \
  __builtin_amdgcn_s_setprio(1);                                                 \
  _Pragma("unroll") for (int m = 0; m < 4; ++m)                                  \
  _Pragma("unroll") for (int nj = 0; nj < 4; ++nj) {                             \
    acc[MI0 + m][nj] = __builtin_amdgcn_mfma_f32_16x16x32_f16(AF[m], BF[nj], acc[MI0 + m][nj], 0, 0, 0); \
  }                                                                              \
  __builtin_amdgcn_s_setprio(0);

  stA(0, 0, 0); stB(0, 0, 0); stB(0, 1, 0); stA(0, 1, 0);
  stB(1, 0, 1); stB(1, 1, 1); stA(1, 0, 1);
  ASM_VMCNT(6);
  SBAR();

  for (int t = 0; t < NKF; ++t) {
    int cur = t & 1;
    // ph0
    f16x8 aL0[4], bk0[4];
#pragma unroll
    for (int m = 0; m < 4; ++m) aL0[m] = *(const f16x8*)(Ab(cur, 0) + aoff[m]);
#pragma unroll
    for (int nj = 0; nj < 4; ++nj) bk0[nj] = *(const f16x8*)(Bb(cur, 0) + boff[nj]);
    if (t + 1 < NKF) stA(cur ^ 1, 1, t + 1);
    SBAR();
    G2_MFMA(0, aL0, bk0)
    SBAR();
    // ph1
    f16x8 aL1[4], bk1[4];
#pragma unroll
    for (int m = 0; m < 4; ++m) aL1[m] = *(const f16x8*)(Ab(cur, 1) + aoff[m]);
#pragma unroll
    for (int nj = 0; nj < 4; ++nj) bk1[nj] = *(const f16x8*)(Bb(cur, 1) + boff[nj]);
    if (t + 2 < NKF) stB(cur, 0, t + 2);
    SBAR();
    G2_MFMA(0, aL1, bk1)
    SBAR();
    // ph2
    f16x8 aH0[4];
#pragma unroll
    for (int m = 0; m < 4; ++m) aH0[m] = *(const f16x8*)(Ab(cur, 0) + aoff[4 + m]);
    if (t + 2 < NKF) stB(cur, 1, t + 2);
    SBAR();
    G2_MFMA(4, aH0, bk0)
    SBAR();
    // ph3
    f16x8 aH1[4];
#pragma unroll
    for (int m = 0; m < 4; ++m) aH1[m] = *(const f16x8*)(Ab(cur, 1) + aoff[4 + m]);
    if (t + 2 < NKF) stA(cur, 0, t + 2);
    SBAR();
    G2_MFMA(4, aH1, bk1)
    if (t + 2 < NKF) { ASM_VMCNT(6); } else { ASM_VMCNT(0); }
    SBAR();
  }
#undef G2_MFMA

#pragma unroll
  for (int mi = 0; mi < 8; ++mi) {
#pragma unroll
    for (int rr = 0; rr < 4; ++rr) {
      int grow = mt * BM + wm + mi * 16 + ls * 4 + rr;
      if (grow < n_e) {
        h16* yrow = y16 + (size_t)(base + grow) * H + (size_t)nt * 256 + wn;
#pragma unroll
        for (int nj = 0; nj < 4; ++nj)
          yrow[nj * 16 + lr] = (h16)acc[mi][nj][rr];
      }
    }
  }
}

extern "C" void kernel_launch(void* const* d_in, const int* in_sizes, int n_in,
                              void* d_out, int out_size, void* d_ws, size_t ws_size,
                              hipStream_t stream) {
  const float* x  = (const float*)d_in[0];
  const float* rl = (const float*)d_in[1];
  const float* w1 = (const float*)d_in[2];
  const float* w3 = (const float*)d_in[3];
  const float* w2 = (const float*)d_in[4];
  float* out = (float*)d_out;

  char* ws = (char*)d_ws;
  size_t off = 0;
  auto alloc = [&](size_t bytes) -> void* {
    void* p = ws + off;
    off = (off + bytes + 255) & ~(size_t)255;
    return p;
  };
  h16*   x16  = (h16*)  alloc((size_t)T * H * sizeof(h16));
  h16*   act  = (h16*)  alloc((size_t)(NENT + SLACK) * F * sizeof(h16));
  int*   etok = (int*)  alloc((size_t)(NENT + SLACK) * sizeof(int));
  float* ew   = (float*)alloc((size_t)(NENT + SLACK) * sizeof(float));
  int*   topi = (int*)  alloc((size_t)NENT * sizeof(int));
  float* topw = (float*)alloc((size_t)NENT * sizeof(float));
  int* tok2ent = (int*) alloc((size_t)NENT * sizeof(int));
  int* counts = (int*)  alloc(64);
  int* offs   = (int*)  alloc(64);
  int* fill   = (int*)  alloc(64);
  h16* w1h = (h16*)alloc((size_t)E * F * H * sizeof(h16));
  h16* w3h = (h16*)alloc((size_t)E * F * H * sizeof(h16));
  h16* w2h = (h16*)alloc((size_t)E * H * F * sizeof(h16));
  h16* y16 = (h16*)alloc((size_t)(NENT + SLACK) * H * sizeof(h16));
  (void)in_sizes; (void)n_in; (void)ws_size;

  k_init_counts<<<1, 64, 0, stream>>>(counts);
  k_route_cvt<<<RT_BLKS + CVT1_BLKS, 256, 0, stream>>>(rl, topi, topw, counts,
                                                       x, x16, w1, w1h, w3, w3h);
  k_prefix<<<1, 64, 0, stream>>>(counts, offs, fill);
  k_scatter<<<(T + 255) / 256, 256, 0, stream>>>(topi, topw, offs, fill, etok, ew, tok2ent);
  k_gemm1<<<NWG1 + CVT2_BLKS, 512, 0, stream>>>(x16, w1h, w3h, counts, offs, etok, act, w2, w2h);
  k_gemm2<<<E * MT256 * NT2b, 512, 0, stream>>>(act, w2h, counts, offs, y16);
  k_combine<<<(T * H / 8) / 256, 256, 0, stream>>>(y16, tok2ent, topw, out);
}

// Round 10
// 585.063 us; speedup vs baseline: 2.5955x; 1.0388x over previous
//
#include <hip/hip_runtime.h>
#include <hip/hip_bf16.h>

typedef _Float16 h16;
typedef _Float16 f16x8 __attribute__((ext_vector_type(8)));
typedef float f32x4 __attribute__((ext_vector_type(4)));

constexpr int T = 8192, H = 1024, F = 2816, E = 8;
constexpr int NENT = T * 2;
constexpr int SLACK = 128;
constexpr int BM = 256, BK = 64;
constexpr int MT256 = T / BM;       // 32
constexpr int NT1b = F / 128;       // 22
constexpr int NT2b = H / 256;       // 4
constexpr int NKH = H / BK;         // 16
constexpr int KS2 = 2;              // gemm2 split-K factor
constexpr int NK2 = F / BK / KS2;   // 22 K-tiles per split
constexpr int NWG1 = E * MT256 * NT1b;   // 5632 gemm1 blocks
constexpr int CVT2_BLKS = 704;           // w2 cvt blocks: 704*512*64 = E*H*F
constexpr int NX = T * H;                // 8388608
constexpr int NW = E * F * H;            // 23068672
constexpr int RT_BLKS = 32;              // routing blocks (32*256 = T)
constexpr int CVT1_BLKS = 2048;          // (NX + 2*NW) / 26624 = 2048 exactly
constexpr int CVT1_PER = 26624;          // elems per cvt block (256*8*13)

#define GLD16(gptr, lptr)                                                        \
  __builtin_amdgcn_global_load_lds(                                              \
      (const __attribute__((address_space(1))) unsigned int*)(gptr),             \
      (__attribute__((address_space(3))) unsigned int*)(lptr), 16, 0, 0)

#define ASM_VMCNT(n) asm volatile("s_waitcnt vmcnt(" #n ")" ::: "memory")
#define SBAR()       __builtin_amdgcn_s_barrier()

// Per-half LDS tile: logical rows x 32 h16 packed as phys [rows/2][64 h16],
// XOR-swizzled 16B slots. Conflict-free with 16x16 frag reads (R2-R6).
__device__ __forceinline__ int lds_off(int row, int s) {
  int r2 = row >> 1;
  int p = (((row & 1) << 2) | s) ^ (r2 & 7);
  return r2 * 128 + p * 16;
}
__device__ __forceinline__ void inv_rowcol(int c, int i, int& row, int& col) {
  int r2 = c * 8 + (i >> 3);
  int slot8 = (i & 7) ^ (r2 & 7);
  row = r2 * 2 + (slot8 >> 2);
  col = (slot8 & 3) * 8;
}
__device__ __forceinline__ f16x8 cvt8(float4 a, float4 b) {
  return f16x8{(h16)a.x, (h16)a.y, (h16)a.z, (h16)a.w,
               (h16)b.x, (h16)b.y, (h16)b.z, (h16)b.w};
}

__global__ void k_init_counts(int* counts) {
  if (threadIdx.x < E) counts[threadIdx.x] = 0;
}

// ---------------- fused routing + x/w1/w3 fp32->fp16 conversion ----------------
__global__ void k_route_cvt(const float* __restrict__ logits,
                            int* __restrict__ top_i, float* __restrict__ top_w,
                            int* __restrict__ counts,
                            const float* __restrict__ x, h16* __restrict__ x16,
                            const float* __restrict__ w1, h16* __restrict__ w1h,
                            const float* __restrict__ w3, h16* __restrict__ w3h) {
  int blk = blockIdx.x;
  if (blk < RT_BLKS) {
    int t = blk * blockDim.x + threadIdx.x;
    if (t >= T) return;
    float l[E];
#pragma unroll
    for (int j = 0; j < E; ++j) l[j] = logits[t * E + j];
    int i1 = 0; float v1 = l[0];
#pragma unroll
    for (int j = 1; j < E; ++j) if (l[j] > v1) { v1 = l[j]; i1 = j; }
    int i2 = -1; float v2 = -3.4e38f;
#pragma unroll
    for (int j = 0; j < E; ++j) if (j != i1 && l[j] > v2) { v2 = l[j]; i2 = j; }
    float e2 = __expf(v2 - v1);
    float inv = 1.0f / (1.0f + e2);
    top_i[2 * t] = i1; top_i[2 * t + 1] = i2;
    top_w[2 * t] = inv; top_w[2 * t + 1] = e2 * inv;
    atomicAdd(&counts[i1], 1);
    atomicAdd(&counts[i2], 1);
    return;
  }
  // conversion blocks: flat range [0, NX + 2*NW), 8 elems/thread, 13 iters
  size_t base = (size_t)(blk - RT_BLKS) * CVT1_PER + threadIdx.x * 8;
#pragma unroll
  for (int it = 0; it < 13; ++it) {
    size_t idx = base + (size_t)it * 2048;
    const float* s; h16* d; size_t o;
    if (idx < (size_t)NX)            { s = x;  d = x16; o = idx; }
    else if (idx < (size_t)NX + NW)  { s = w1; d = w1h; o = idx - NX; }
    else                             { s = w3; d = w3h; o = idx - NX - NW; }
    float4 a = *(const float4*)(s + o);
    float4 b = *(const float4*)(s + o + 4);
    *(f16x8*)(d + o) = cvt8(a, b);
  }
}

__global__ void k_prefix(const int* __restrict__ counts, int* __restrict__ offs,
                         int* __restrict__ fill) {
  if (threadIdx.x == 0) {
    int s = 0;
    for (int e = 0; e < E; ++e) { offs[e] = s; s += counts[e]; fill[e] = 0; }
  }
}

__global__ void k_scatter(const int* __restrict__ top_i, const float* __restrict__ top_w,
                          const int* __restrict__ offs, int* __restrict__ fill,
                          int* __restrict__ etok, float* __restrict__ ew,
                          int* __restrict__ tok2ent) {
  int t = blockIdx.x * blockDim.x + threadIdx.x;
  if (t >= T) return;
#pragma unroll
  for (int k = 0; k < 2; ++k) {
    int e = top_i[2 * t + k];
    int pos = atomicAdd(&fill[e], 1);
    int idx = offs[e] + pos;
    etok[idx] = t;
    ew[idx] = top_w[2 * t + k];
    tok2ent[2 * t + k] = idx;
  }
}

// ---------------- combine: out[t] = w0*(ya[p0]+yb[p0]) + w1*(ya[p1]+yb[p1]) ----------------
__global__ void k_combine(const h16* __restrict__ ya, const h16* __restrict__ yb,
                          const int* __restrict__ tok2ent,
                          const float* __restrict__ topw, float* __restrict__ out) {
  int i = blockIdx.x * blockDim.x + threadIdx.x;
  int t = i >> 7;
  int h0 = (i & 127) << 3;
  int p0 = tok2ent[2 * t], p1 = tok2ent[2 * t + 1];
  float w0 = topw[2 * t], w1 = topw[2 * t + 1];
  f16x8 a0 = *(const f16x8*)(ya + (size_t)p0 * H + h0);
  f16x8 b0 = *(const f16x8*)(yb + (size_t)p0 * H + h0);
  f16x8 a1 = *(const f16x8*)(ya + (size_t)p1 * H + h0);
  f16x8 b1 = *(const f16x8*)(yb + (size_t)p1 * H + h0);
  float4 o0, o1;
  o0.x = w0 * ((float)a0[0] + (float)b0[0]) + w1 * ((float)a1[0] + (float)b1[0]);
  o0.y = w0 * ((float)a0[1] + (float)b0[1]) + w1 * ((float)a1[1] + (float)b1[1]);
  o0.z = w0 * ((float)a0[2] + (float)b0[2]) + w1 * ((float)a1[2] + (float)b1[2]);
  o0.w = w0 * ((float)a0[3] + (float)b0[3]) + w1 * ((float)a1[3] + (float)b1[3]);
  o1.x = w0 * ((float)a0[4] + (float)b0[4]) + w1 * ((float)a1[4] + (float)b1[4]);
  o1.y = w0 * ((float)a0[5] + (float)b0[5]) + w1 * ((float)a1[5] + (float)b1[5]);
  o1.z = w0 * ((float)a0[6] + (float)b0[6]) + w1 * ((float)a1[6] + (float)b1[6]);
  o1.w = w0 * ((float)a0[7] + (float)b0[7]) + w1 * ((float)a1[7] + (float)b1[7]);
  *(float4*)(out + (size_t)t * H + h0) = o0;
  *(float4*)(out + (size_t)t * H + h0 + 4) = o1;
}

// ---------------- GEMM1: 256x(128x2), 4-phase/K-tile (R6) + w2-cvt tail blocks ----------------
// LDS per dbuf (64KB): A-kh0 16K | A-kh1 16K | B1-kh0 8K | B1-kh1 8K | B3-kh0 8K | B3-kh1 8K
__launch_bounds__(512, 2)
__global__ void k_gemm1(const h16* __restrict__ x16,
                        const h16* __restrict__ w1h, const h16* __restrict__ w3h,
                        const int* __restrict__ counts, const int* __restrict__ offs,
                        const int* __restrict__ etok, h16* __restrict__ act,
                        const float* __restrict__ w2f, h16* __restrict__ w2h) {
  int orig = blockIdx.x;
  if (orig >= NWG1) {
    // w2 fp32->fp16 conversion: 704 blocks x 512 thr x 8 elems x 8 iters
    size_t base = (size_t)(orig - NWG1) * (512 * 64) + threadIdx.x * 8;
#pragma unroll
    for (int it = 0; it < 8; ++it) {
      size_t o = base + (size_t)it * (512 * 8);
      float4 a = *(const float4*)(w2f + o);
      float4 b = *(const float4*)(w2f + o + 4);
      *(f16x8*)(w2h + o) = cvt8(a, b);
    }
    return;
  }
  int bid = (orig & 7) * (NWG1 / 8) + (orig >> 3);   // XCD-chunked swizzle
  int e  = bid / (MT256 * NT1b);
  int r  = bid % (MT256 * NT1b);
  int nt = r / MT256;
  int mt = r % MT256;
  int n_e = counts[e];
  if (mt * BM >= n_e) return;
  int base = offs[e];

  __shared__ char lds[131072];

  int tid = threadIdx.x;
  int lane = tid & 63, wid = tid >> 6;
  int wm = (wid >> 2) * 128;
  int wn = (wid & 3) * 32;
  int lr = lane & 15, ls = lane >> 4;

  auto Ab  = [&](int d, int h) -> char* { return lds + d * 65536 + h * 16384; };
  auto B1b = [&](int d, int h) -> char* { return lds + d * 65536 + 32768 + h * 8192; };
  auto B3b = [&](int d, int h) -> char* { return lds + d * 65536 + 49152 + h * 8192; };

  const h16* gA[2];
#pragma unroll
  for (int j = 0; j < 2; ++j) {
    int row, col;
    inv_rowcol(2 * wid + j, lane, row, col);
    int gr = mt * BM + row; if (gr >= n_e) gr = n_e - 1;
    gA[j] = x16 + (size_t)etok[base + gr] * H + col;
  }
  const h16 *gB1, *gB3;
  {
    int row, col;
    inv_rowcol(wid, lane, row, col);
    size_t w = ((size_t)e * F + (size_t)nt * 128 + row) * H + col;
    gB1 = w1h + w;
    gB3 = w3h + w;
  }

  auto stA = [&](int d, int h, int kt) {
#pragma unroll
    for (int j = 0; j < 2; ++j)
      GLD16(gA[j] + kt * 64 + h * 32, Ab(d, h) + (2 * wid + j) * 1024);
  };
  auto stB = [&](int d, int h, int kt) {
    GLD16(gB1 + kt * 64 + h * 32, B1b(d, h) + wid * 1024);
    GLD16(gB3 + kt * 64 + h * 32, B3b(d, h) + wid * 1024);
  };

  int aoff[8], boff[2];
#pragma unroll
  for (int mi = 0; mi < 8; ++mi) aoff[mi] = lds_off(wm + mi * 16 + lr, ls);
#pragma unroll
  for (int nj = 0; nj < 2; ++nj) boff[nj] = lds_off(wn + nj * 16 + lr, ls);

  f32x4 ag[8][2] = {{{0.f,0.f,0.f,0.f}}};
  f32x4 au[8][2] = {{{0.f,0.f,0.f,0.f}}};

#define G1_MFMA(MI0, AF, B1F, B3F)                                               \
  __builtin_amdgcn_s_setprio(1);                                                 \
  _Pragma("unroll") for (int m = 0; m < 4; ++m)                                  \
  _Pragma("unroll") for (int nj = 0; nj < 2; ++nj) {                             \
    ag[MI0 + m][nj] = __builtin_amdgcn_mfma_f32_16x16x32_f16(AF[m], B1F[nj], ag[MI0 + m][nj], 0, 0, 0); \
    au[MI0 + m][nj] = __builtin_amdgcn_mfma_f32_16x16x32_f16(AF[m], B3F[nj], au[MI0 + m][nj], 0, 0, 0); \
  }                                                                              \
  __builtin_amdgcn_s_setprio(0);

  // prologue: tile0 fully (8), tile1 all but A-kh1 (6)
  stA(0, 0, 0); stB(0, 0, 0); stB(0, 1, 0); stA(0, 1, 0);
  stB(1, 0, 1); stB(1, 1, 1); stA(1, 0, 1);
  ASM_VMCNT(6);
  SBAR();

  for (int t = 0; t < NKH; ++t) {
    int cur = t & 1;
    // ph0: A[0-3]kh0 + B kh0 reads; stage A-kh1(t+1) -> dbuf cur^1
    f16x8 aL0[4], b1k0[2], b3k0[2];
#pragma unroll
    for (int m = 0; m < 4; ++m) aL0[m] = *(const f16x8*)(Ab(cur, 0) + aoff[m]);
#pragma unroll
    for (int nj = 0; nj < 2; ++nj) {
      b1k0[nj] = *(const f16x8*)(B1b(cur, 0) + boff[nj]);
      b3k0[nj] = *(const f16x8*)(B3b(cur, 0) + boff[nj]);
    }
    if (t + 1 < NKH) stA(cur ^ 1, 1, t + 1);
    SBAR();
    G1_MFMA(0, aL0, b1k0, b3k0)
    SBAR();
    // ph1: A[0-3]kh1 + B kh1 reads; stage B-kh0(t+2) -> cur
    f16x8 aL1[4], b1k1[2], b3k1[2];
#pragma unroll
    for (int m = 0; m < 4; ++m) aL1[m] = *(const f16x8*)(Ab(cur, 1) + aoff[m]);
#pragma unroll
    for (int nj = 0; nj < 2; ++nj) {
      b1k1[nj] = *(const f16x8*)(B1b(cur, 1) + boff[nj]);
      b3k1[nj] = *(const f16x8*)(B3b(cur, 1) + boff[nj]);
    }
    if (t + 2 < NKH) stB(cur, 0, t + 2);
    SBAR();
    G1_MFMA(0, aL1, b1k1, b3k1)
    SBAR();
    // ph2: A[4-7]kh0 reads; stage B-kh1(t+2) -> cur
    f16x8 aH0[4];
#pragma unroll
    for (int m = 0; m < 4; ++m) aH0[m] = *(const f16x8*)(Ab(cur, 0) + aoff[4 + m]);
    if (t + 2 < NKH) stB(cur, 1, t + 2);
    SBAR();
    G1_MFMA(4, aH0, b1k0, b3k0)
    SBAR();
    // ph3: A[4-7]kh1 reads; stage A-kh0(t+2) -> cur; counted vmcnt
    f16x8 aH1[4];
#pragma unroll
    for (int m = 0; m < 4; ++m) aH1[m] = *(const f16x8*)(Ab(cur, 1) + aoff[4 + m]);
    if (t + 2 < NKH) stA(cur, 0, t + 2);
    SBAR();
    G1_MFMA(4, aH1, b1k1, b3k1)
    if (t + 2 < NKH) { ASM_VMCNT(6); } else { ASM_VMCNT(0); }
    SBAR();
  }
#undef G1_MFMA

  // epilogue: silu(g)*u -> act fp16
#pragma unroll
  for (int mi = 0; mi < 8; ++mi) {
#pragma unroll
    for (int rr = 0; rr < 4; ++rr) {
      int grow = mt * BM + wm + mi * 16 + ls * 4 + rr;
      if (grow < n_e) {
        size_t rowb = (size_t)(base + grow) * F + (size_t)nt * 128 + wn;
#pragma unroll
        for (int nj = 0; nj < 2; ++nj) {
          float g = ag[mi][nj][rr];
          float u = au[mi][nj][rr];
          float s = g / (1.0f + __expf(-g)) * u;
          act[rowb + nj * 16 + lr] = (h16)s;
        }
      }
    }
  }
}

// ---------------- GEMM2: 256x256, 4-phase/K-tile, split-K=2 ----------------
// LDS per dbuf (64KB): A-kh0 16K | A-kh1 16K | B-kh0 16K | B-kh1 16K
__launch_bounds__(512, 2)
__global__ void k_gemm2(const h16* __restrict__ act, const h16* __restrict__ w2h,
                        const int* __restrict__ counts, const int* __restrict__ offs,
                        h16* __restrict__ ya, h16* __restrict__ yb) {
  constexpr int NWG = E * MT256 * NT2b * KS2;        // 2048, %8==0
  int orig = blockIdx.x;
  int bid = (orig & 7) * (NWG / 8) + (orig >> 3);
  int ks = bid / (E * MT256 * NT2b);
  int r0 = bid % (E * MT256 * NT2b);
  int e  = r0 / (MT256 * NT2b);
  int r  = r0 % (MT256 * NT2b);
  int nt = r / MT256;
  int mt = r % MT256;
  int n_e = counts[e];
  if (mt * BM >= n_e) return;
  int base = offs[e];
  h16* yout = ks ? yb : ya;

  __shared__ char lds[131072];

  int tid = threadIdx.x;
  int lane = tid & 63, wid = tid >> 6;
  int wm = (wid >> 2) * 128;
  int wn = (wid & 3) * 64;
  int lr = lane & 15, ls = lane >> 4;

  auto Ab = [&](int d, int h) -> char* { return lds + d * 65536 + h * 16384; };
  auto Bb = [&](int d, int h) -> char* { return lds + d * 65536 + 32768 + h * 16384; };

  const h16* gA[2]; const h16* gB[2];
#pragma unroll
  for (int j = 0; j < 2; ++j) {
    int row, col;
    inv_rowcol(2 * wid + j, lane, row, col);
    int gr = mt * BM + row; if (gr >= n_e) gr = n_e - 1;
    gA[j] = act + (size_t)(base + gr) * F + col + ks * (NK2 * BK);
    gB[j] = w2h + ((size_t)e * H + (size_t)nt * 256 + row) * F + col + ks * (NK2 * BK);
  }

  auto stA = [&](int d, int h, int kt) {
#pragma unroll
    for (int j = 0; j < 2; ++j)
      GLD16(gA[j] + kt * 64 + h * 32, Ab(d, h) + (2 * wid + j) * 1024);
  };
  auto stB = [&](int d, int h, int kt) {
#pragma unroll
    for (int j = 0; j < 2; ++j)
      GLD16(gB[j] + kt * 64 + h * 32, Bb(d, h) + (2 * wid + j) * 1024);
  };

  int aoff[8], boff[4];
#pragma unroll
  for (int mi = 0; mi < 8; ++mi) aoff[mi] = lds_off(wm + mi * 16 + lr, ls);
#pragma unroll
  for (int nj = 0; nj < 4; ++nj) boff[nj] = lds_off(wn + nj * 16 + lr, ls);

  f32x4 acc[8][4] = {{{0.f,0.f,0.f,0.f}}};

#define G2_MFMA(MI0, AF, BF)                                                     \
  __builtin_amdgcn_s_setprio(1);                                                 \
  _Pragma("unroll") for (int m = 0; m < 4; ++m)                                  \
  _Pragma("unroll") for (int nj = 0; nj < 4; ++nj) {                             \
    acc[MI0 + m][nj] = __builtin_amdgcn_mfma_f32_16x16x32_f16(AF[m], BF[nj], acc[MI0 + m][nj], 0, 0, 0); \
  }                                                                              \
  __builtin_amdgcn_s_setprio(0);

  stA(0, 0, 0); stB(0, 0, 0); stB(0, 1, 0); stA(0, 1, 0);
  stB(1, 0, 1); stB(1, 1, 1); stA(1, 0, 1);
  ASM_VMCNT(6);
  SBAR();

  for (int t = 0; t < NK2; ++t) {
    int cur = t & 1;
    // ph0
    f16x8 aL0[4], bk0[4];
#pragma unroll
    for (int m = 0; m < 4; ++m) aL0[m] = *(const f16x8*)(Ab(cur, 0) + aoff[m]);
#pragma unroll
    for (int nj = 0; nj < 4; ++nj) bk0[nj] = *(const f16x8*)(Bb(cur, 0) + boff[nj]);
    if (t + 1 < NK2) stA(cur ^ 1, 1, t + 1);
    SBAR();
    G2_MFMA(0, aL0, bk0)
    SBAR();
    // ph1
    f16x8 aL1[4], bk1[4];
#pragma unroll
    for (int m = 0; m < 4; ++m) aL1[m] = *(const f16x8*)(Ab(cur, 1) + aoff[m]);
#pragma unroll
    for (int nj = 0; nj < 4; ++nj) bk1[nj] = *(const f16x8*)(Bb(cur, 1) + boff[nj]);
    if (t + 2 < NK2) stB(cur, 0, t + 2);
    SBAR();
    G2_MFMA(0, aL1, bk1)
    SBAR();
    // ph2
    f16x8 aH0[4];
#pragma unroll
    for (int m = 0; m < 4; ++m) aH0[m] = *(const f16x8*)(Ab(cur, 0) + aoff[4 + m]);
    if (t + 2 < NK2) stB(cur, 1, t + 2);
    SBAR();
    G2_MFMA(4, aH0, bk0)
    SBAR();
    // ph3
    f16x8 aH1[4];
#pragma unroll
    for (int m = 0; m < 4; ++m) aH1[m] = *(const f16x8*)(Ab(cur, 1) + aoff[4 + m]);
    if (t + 2 < NK2) stA(cur, 0, t + 2);
    SBAR();
    G2_MFMA(4, aH1, bk1)
    if (t + 2 < NK2) { ASM_VMCNT(6); } else { ASM_VMCNT(0); }
    SBAR();
  }
#undef G2_MFMA

#pragma unroll
  for (int mi = 0; mi < 8; ++mi) {
#pragma unroll
    for (int rr = 0; rr < 4; ++rr) {
      int grow = mt * BM + wm + mi * 16 + ls * 4 + rr;
      if (grow < n_e) {
        h16* yrow = yout + (size_t)(base + grow) * H + (size_t)nt * 256 + wn;
#pragma unroll
        for (int nj = 0; nj < 4; ++nj)
          yrow[nj * 16 + lr] = (h16)acc[mi][nj][rr];
      }
    }
  }
}

extern "C" void kernel_launch(void* const* d_in, const int* in_sizes, int n_in,
                              void* d_out, int out_size, void* d_ws, size_t ws_size,
                              hipStream_t stream) {
  const float* x  = (const float*)d_in[0];
  const float* rl = (const float*)d_in[1];
  const float* w1 = (const float*)d_in[2];
  const float* w3 = (const float*)d_in[3];
  const float* w2 = (const float*)d_in[4];
  float* out = (float*)d_out;

  char* ws = (char*)d_ws;
  size_t off = 0;
  auto alloc = [&](size_t bytes) -> void* {
    void* p = ws + off;
    off = (off + bytes + 255) & ~(size_t)255;
    return p;
  };
  h16*   x16  = (h16*)  alloc((size_t)T * H * sizeof(h16));
  h16*   act  = (h16*)  alloc((size_t)(NENT + SLACK) * F * sizeof(h16));
  int*   etok = (int*)  alloc((size_t)(NENT + SLACK) * sizeof(int));
  float* ew   = (float*)alloc((size_t)(NENT + SLACK) * sizeof(float));
  int*   topi = (int*)  alloc((size_t)NENT * sizeof(int));
  float* topw = (float*)alloc((size_t)NENT * sizeof(float));
  int* tok2ent = (int*) alloc((size_t)NENT * sizeof(int));
  int* counts = (int*)  alloc(64);
  int* offs   = (int*)  alloc(64);
  int* fill   = (int*)  alloc(64);
  h16* w1h = (h16*)alloc((size_t)E * F * H * sizeof(h16));
  h16* w3h = (h16*)alloc((size_t)E * F * H * sizeof(h16));
  h16* w2h = (h16*)alloc((size_t)E * H * F * sizeof(h16));
  h16* ya  = (h16*)alloc((size_t)(NENT + SLACK) * H * sizeof(h16));
  h16* yb  = (h16*)alloc((size_t)(NENT + SLACK) * H * sizeof(h16));
  (void)in_sizes; (void)n_in; (void)ws_size;

  k_init_counts<<<1, 64, 0, stream>>>(counts);
  k_route_cvt<<<RT_BLKS + CVT1_BLKS, 256, 0, stream>>>(rl, topi, topw, counts,
                                                       x, x16, w1, w1h, w3, w3h);
  k_prefix<<<1, 64, 0, stream>>>(counts, offs, fill);
  k_scatter<<<(T + 255) / 256, 256, 0, stream>>>(topi, topw, offs, fill, etok, ew, tok2ent);
  k_gemm1<<<NWG1 + CVT2_BLKS, 512, 0, stream>>>(x16, w1h, w3h, counts, offs, etok, act, w2, w2h);
  k_gemm2<<<E * MT256 * NT2b * KS2, 512, 0, stream>>>(act, w2h, counts, offs, ya, yb);
  k_combine<<<(T * H / 8) / 256, 256, 0, stream>>>(ya, yb, tok2ent, topw, out);
}